// Round 12
// baseline (1273.915 us; speedup 1.0000x reference)
//
#include <hip/hip_runtime.h>

static constexpr int KIN   = 25;
static constexpr int KOUT  = 5;
static constexpr int NBLK2 = 2048;     // blocks for hist/scatter roles
static constexpr int BSH   = 9;        // log2 nodes per bucket
static constexpr int NPB   = 1 << BSH; // 512
static constexpr int NBH   = 2048;     // table stride (max buckets)
static constexpr int BROW  = NBH + 1;
static constexpr int CAP   = 5120;     // LDS sort capacity (16 sigma)

// roles
#define M_NONE -1
#define M_NODE 0
#define M_HIST 1
#define M_SUMO 2
#define M_SCAN 3
#define M_SCAT 4
#define M_GATH 5
#define M_MLP  6

// ---------------------------------------------------------------------------
// k_combo: grid-partitioned multi-role kernel. Up to 3 segments per launch;
// block bx picks its (mode, rel) from the segment table. Dynamic LDS.
// hist table for relation r overlays xout[r] (dead until gather r).
// slotmul: 1 = per-rel xl8/xr5/rs slots (fused), 0 = shared slot 0 (fallback).
// ---------------------------------------------------------------------------
__global__ __launch_bounds__(256) void k_combo(
    int m0, int r0, int n0, int m1, int r1, int n1, int m2, int r2, int n2,
    const float* __restrict__ x,
    const int* __restrict__ e0, const int* __restrict__ e1,
    const int* __restrict__ e2,
    const float* __restrict__ Wl0, const float* __restrict__ Wr0,
    const float* __restrict__ Wl1, const float* __restrict__ Wr1,
    const float* __restrict__ Wl2, const float* __restrict__ Wr2,
    const float* __restrict__ at0, const float* __restrict__ at1,
    const float* __restrict__ at2,
    const float* __restrict__ bi0, const float* __restrict__ bi1,
    const float* __restrict__ bi2,
    const float* __restrict__ Wp1, const float* __restrict__ bp1,
    const float* __restrict__ Wp2, const float* __restrict__ bp2,
    const float* __restrict__ Wc1, const float* __restrict__ bc1,
    const float* __restrict__ Wc2, const float* __restrict__ bc2,
    float* __restrict__ xl8a, float* __restrict__ xr5a,
    int* __restrict__ rs3, int slotmul,
    int* __restrict__ totals3, int* __restrict__ base3,
    float* __restrict__ xout, float* __restrict__ outp,
    int n, int E, int NB)
{
    extern __shared__ char smem_raw[];
    int bx = blockIdx.x;
    int mode, rel;
    if (bx < n0)            { mode = m0; rel = r0; }
    else if (bx < n0 + n1)  { mode = m1; rel = r1; bx -= n0; }
    else                    { mode = m2; rel = r2; bx -= n0 + n1; }
    const int tid = threadIdx.x;

    // ======================= NODE =======================
    if (mode == M_NODE) {
        float* sW = (float*)smem_raw;            // 6 x 125 (768 stride)
        float* sx = sW + 768;                    // 256 x 25
        if (rel < 0) {
            if (tid < KIN * KOUT) {
                sW[tid]       = Wl0[tid]; sW[125 + tid] = Wr0[tid];
                sW[250 + tid] = Wl1[tid]; sW[375 + tid] = Wr1[tid];
                sW[500 + tid] = Wl2[tid]; sW[625 + tid] = Wr2[tid];
            }
        } else {
            const float* Wl = (rel == 0) ? Wl0 : (rel == 1 ? Wl1 : Wl2);
            const float* Wr = (rel == 0) ? Wr0 : (rel == 1 ? Wr1 : Wr2);
            if (tid < KIN * KOUT) { sW[tid] = Wl[tid]; sW[125 + tid] = Wr[tid]; }
        }
        const int NR = (rel < 0) ? 3 : 1;
        for (int sub = 0; sub < 4; ++sub) {
            const int base = bx * 1024 + sub * 256;
            if (base >= n) break;
            const int cnt = min(256, n - base);
            __syncthreads();
            const size_t xb = (size_t)base * KIN;
            for (int i = tid; i < cnt * KIN; i += 256) sx[i] = x[xb + i];
            __syncthreads();
            if (tid < cnt) {
                const int node = base + tid;
                float xls[3][KOUT] = {};
                float xrs[3][KOUT] = {};
                const float* xp = &sx[tid * KIN];
#pragma unroll
                for (int i = 0; i < KIN; ++i) {
                    const float xv = xp[i];
                    for (int r = 0; r < NR; ++r)
#pragma unroll
                        for (int o = 0; o < KOUT; ++o) {
                            xls[r][o] += xv * sW[r * 250 + i * KOUT + o];
                            xrs[r][o] += xv * sW[r * 250 + 125 + i * KOUT + o];
                        }
                }
                for (int r = 0; r < NR; ++r) {
                    const size_t n8 = (size_t)r * n * 8 + (size_t)node * 8;
                    float4 v4;
                    v4.x = xls[r][0]; v4.y = xls[r][1];
                    v4.z = xls[r][2]; v4.w = xls[r][3];
                    *(float4*)(xl8a + n8) = v4;
                    xl8a[n8 + 4] = xls[r][4];
                    const size_t n5 = (size_t)r * n * 5 + (size_t)node * 5;
#pragma unroll
                    for (int o = 0; o < KOUT; ++o) xr5a[n5 + o] = xrs[r][o];
                }
            }
        }
        return;
    }

    // ======================= HIST =======================
    if (mode == M_HIST) {
        int* h = (int*)smem_raw;                 // NB ints
        const int* dst = ((rel == 0) ? e0 : (rel == 1) ? e1 : e2) + E;
        int* hist_blk = (int*)(xout + (size_t)rel * 5 * n);
        for (int i = tid; i < NB; i += 256) h[i] = 0;
        __syncthreads();
        const int chunk = (((E + NBLK2 - 1) / NBLK2) + 3) & ~3;
        const int eb = bx * chunk, ee = min(E, eb + chunk);
        const int vend = eb + ((ee - eb) & ~3);
        for (int i = eb + tid * 4; i < vend; i += 1024) {
            const int4 d4 = *(const int4*)(dst + i);
            atomicAdd(&h[d4.x >> BSH], 1);
            atomicAdd(&h[d4.y >> BSH], 1);
            atomicAdd(&h[d4.z >> BSH], 1);
            atomicAdd(&h[d4.w >> BSH], 1);
        }
        for (int i = vend + tid; i < ee; i += 256)
            atomicAdd(&h[dst[i] >> BSH], 1);
        __syncthreads();
        for (int i = tid; i < NB; i += 256) hist_blk[(size_t)bx * NBH + i] = h[i];
        return;
    }

    // ======================= SUMOFFS =======================
    if (mode == M_SUMO) {
        int* hist_blk = (int*)(xout + (size_t)rel * 5 * n);
        int* totals   = totals3 + rel * NBH;
        const int i = bx * 256 + tid;
        if (i >= NBH) return;
        if (i >= NB) { totals[i] = 0; return; }
        int s = 0;
        for (int b = 0; b < NBLK2; ++b) {
            const int t = hist_blk[(size_t)b * NBH + i];
            hist_blk[(size_t)b * NBH + i] = s;
            s += t;
        }
        totals[i] = s;
        return;
    }

    // ======================= SCAN =======================
    if (mode == M_SCAN) {
        int* s = (int*)smem_raw;                 // 256 ints
        const int* totals = totals3 + rel * NBH;
        int* base = base3 + rel * BROW;
        int loc[8];
        int sum = 0;
#pragma unroll
        for (int j = 0; j < 8; ++j) { loc[j] = totals[tid * 8 + j]; sum += loc[j]; }
        s[tid] = sum;
        __syncthreads();
        for (int off = 1; off < 256; off <<= 1) {
            const int v = (tid >= off) ? s[tid - off] : 0;
            __syncthreads();
            s[tid] += v;
            __syncthreads();
        }
        int run = s[tid] - sum;
#pragma unroll
        for (int j = 0; j < 8; ++j) { base[tid * 8 + j] = run; run += loc[j]; }
        if (tid == 255) base[NBH] = E;
        return;
    }

    // ======================= SCATTER =======================
    if (mode == M_SCAT) {
        int* cur = (int*)smem_raw;               // NB ints
        const int* src = (rel == 0) ? e0 : (rel == 1) ? e1 : e2;
        const int* dst = src + E;
        const int* hist_blk = (const int*)(xout + (size_t)rel * 5 * n);
        const int* base = base3 + rel * BROW;
        int* rs = rs3 + (size_t)rel * slotmul * E;

        for (int i = tid; i < NB; i += 256)
            cur[i] = base[i] + hist_blk[(size_t)bx * NBH + i];
        __syncthreads();
        const int chunk = (((E + NBLK2 - 1) / NBLK2) + 3) & ~3;
        const int eb = bx * chunk, ee = min(E, eb + chunk);
        const int vend = eb + ((ee - eb) & ~3);
        for (int i = eb + tid * 4; i < vend; i += 1024) {
            const int4 s4 = *(const int4*)(src + i);
            const int4 d4 = *(const int4*)(dst + i);
            int p;
            p = atomicAdd(&cur[d4.x >> BSH], 1); rs[p] = (s4.x << BSH) | (d4.x & (NPB - 1));
            p = atomicAdd(&cur[d4.y >> BSH], 1); rs[p] = (s4.y << BSH) | (d4.y & (NPB - 1));
            p = atomicAdd(&cur[d4.z >> BSH], 1); rs[p] = (s4.z << BSH) | (d4.z & (NPB - 1));
            p = atomicAdd(&cur[d4.w >> BSH], 1); rs[p] = (s4.w << BSH) | (d4.w & (NPB - 1));
        }
        for (int i = vend + tid; i < ee; i += 256) {
            const int d = dst[i];
            const int p = atomicAdd(&cur[d >> BSH], 1);
            rs[p] = (src[i] << BSH) | (d & (NPB - 1));
        }
        return;
    }

    // ======================= GATHER =======================
    if (mode == M_GATH) {
        float* acc    = (float*)smem_raw;        // NPB*6
        float* xrw    = acc + NPB * 6;           // NPB*5
        int*   cur    = (int*)(xrw + NPB * 5);   // NPB
        int*   sorted = cur + NPB;               // CAP
        int*   sc     = sorted + CAP;            // 256

        const int bkt = bx;
        const int*   rs   = rs3 + (size_t)rel * slotmul * E;
        const int*   base = base3 + rel * BROW;
        const float* xl8  = xl8a + (size_t)rel * slotmul * 8 * n;
        const float* xr5  = xr5a + (size_t)rel * slotmul * 5 * n;
        const float* att  = (rel == 0) ? at0 : (rel == 1 ? at1 : at2);
        const float* bias = (rel == 0) ? bi0 : (rel == 1 ? bi1 : bi2);
        float*       xo   = xout + (size_t)rel * 5 * n;

        const int node0 = bkt << BSH;
        const int nn = min(NPB, n - node0);

        for (int i = tid; i < NPB * 6; i += 256) acc[i] = 0.f;
        for (int i = tid; i < nn * 5; i += 256) xrw[i] = xr5[(size_t)node0 * 5 + i];
        for (int i = tid; i < NPB; i += 256) cur[i] = 0;
        __syncthreads();

        const float a0 = att[0], a1 = att[1], a2 = att[2], a3 = att[3], a4 = att[4];
        const int eb = base[bkt], ee = base[bkt + 1];
        const int seg = ee - eb;

        if (seg > 0 && seg <= CAP) {
            for (int i = eb + tid; i < ee; i += 256)
                atomicAdd(&cur[rs[i] & (NPB - 1)], 1);
            __syncthreads();
            const int h0 = cur[2 * tid], h1 = cur[2 * tid + 1];
            const int pair = h0 + h1;
            sc[tid] = pair;
            __syncthreads();
            for (int off = 1; off < 256; off <<= 1) {
                const int v = (tid >= off) ? sc[tid - off] : 0;
                __syncthreads();
                sc[tid] += v;
                __syncthreads();
            }
            const int excl = sc[tid] - pair;
            cur[2 * tid] = excl;
            cur[2 * tid + 1] = excl + h0;
            __syncthreads();
            for (int i = eb + tid; i < ee; i += 256) {
                const int v = rs[i];
                const int p = atomicAdd(&cur[v & (NPB - 1)], 1);
                sorted[p] = v;
            }
            __syncthreads();
            const int C  = (seg + 255) / 256;
            const int s0 = tid * C;
            const int s1 = min(seg, s0 + C);
            int curdl = -1;
            float A0 = 0.f, A1 = 0.f, A2 = 0.f, A3 = 0.f, A4 = 0.f, A5 = 0.f;
            float xr0 = 0.f, xr1 = 0.f, xr2 = 0.f, xr3 = 0.f, xr4 = 0.f;
            for (int i = s0; i < s1; ++i) {
                const int v  = sorted[i];
                const int dl = v & (NPB - 1);
                const int s  = v >> BSH;
                const size_t s8 = (size_t)s * 8;
                const float4 xs = *(const float4*)(xl8 + s8);
                const float  xs4 = xl8[s8 + 4];
                if (dl != curdl) {
                    if (curdl >= 0) {
                        atomicAdd(&acc[curdl * 6 + 0], A0);
                        atomicAdd(&acc[curdl * 6 + 1], A1);
                        atomicAdd(&acc[curdl * 6 + 2], A2);
                        atomicAdd(&acc[curdl * 6 + 3], A3);
                        atomicAdd(&acc[curdl * 6 + 4], A4);
                        atomicAdd(&acc[curdl * 6 + 5], A5);
                    }
                    curdl = dl;
                    A0 = A1 = A2 = A3 = A4 = A5 = 0.f;
                    const float* xr = &xrw[dl * 5];
                    xr0 = xr[0]; xr1 = xr[1]; xr2 = xr[2]; xr3 = xr[3]; xr4 = xr[4];
                }
                float t, lg = 0.f;
                t = xs.x + xr0; t = (t >= 0.f) ? t : 0.2f * t; lg += t * a0;
                t = xs.y + xr1; t = (t >= 0.f) ? t : 0.2f * t; lg += t * a1;
                t = xs.z + xr2; t = (t >= 0.f) ? t : 0.2f * t; lg += t * a2;
                t = xs.w + xr3; t = (t >= 0.f) ? t : 0.2f * t; lg += t * a3;
                t = xs4  + xr4; t = (t >= 0.f) ? t : 0.2f * t; lg += t * a4;
                const float w = __expf(lg);
                A0 += w * xs.x; A1 += w * xs.y; A2 += w * xs.z;
                A3 += w * xs.w; A4 += w * xs4;  A5 += w;
            }
            if (curdl >= 0) {
                atomicAdd(&acc[curdl * 6 + 0], A0);
                atomicAdd(&acc[curdl * 6 + 1], A1);
                atomicAdd(&acc[curdl * 6 + 2], A2);
                atomicAdd(&acc[curdl * 6 + 3], A3);
                atomicAdd(&acc[curdl * 6 + 4], A4);
                atomicAdd(&acc[curdl * 6 + 5], A5);
            }
            __syncthreads();
        } else if (seg > CAP) {
            for (int i = eb + tid; i < ee; i += 256) {
                const int v  = rs[i];
                const int s  = v >> BSH;
                const int dl = v & (NPB - 1);
                const size_t s8 = (size_t)s * 8;
                const float4 xs = *(const float4*)(xl8 + s8);
                const float  xs4 = xl8[s8 + 4];
                const float* xr = &xrw[dl * 5];
                float t, lg = 0.f;
                t = xs.x + xr[0]; t = (t >= 0.f) ? t : 0.2f * t; lg += t * a0;
                t = xs.y + xr[1]; t = (t >= 0.f) ? t : 0.2f * t; lg += t * a1;
                t = xs.z + xr[2]; t = (t >= 0.f) ? t : 0.2f * t; lg += t * a2;
                t = xs.w + xr[3]; t = (t >= 0.f) ? t : 0.2f * t; lg += t * a3;
                t = xs4  + xr[4]; t = (t >= 0.f) ? t : 0.2f * t; lg += t * a4;
                const float w = __expf(lg);
                atomicAdd(&acc[dl * 6 + 0], w * xs.x);
                atomicAdd(&acc[dl * 6 + 1], w * xs.y);
                atomicAdd(&acc[dl * 6 + 2], w * xs.z);
                atomicAdd(&acc[dl * 6 + 3], w * xs.w);
                atomicAdd(&acc[dl * 6 + 4], w * xs4);
                atomicAdd(&acc[dl * 6 + 5], w);
            }
            __syncthreads();
        } else {
            __syncthreads();
        }

        const float b0 = bias[0], b1 = bias[1], b2 = bias[2],
                    b3 = bias[3], b4 = bias[4];
        for (int l = tid; l < nn; l += 256) {
            const int node = node0 + l;
            const size_t s8 = (size_t)node * 8;
            const float4 xs = *(const float4*)(xl8 + s8);
            const float  xs4 = xl8[s8 + 4];
            const float* xr = &xrw[l * 5];

            float t, lg = 0.f;
            t = xs.x + xr[0]; t = (t >= 0.f) ? t : 0.2f * t; lg += t * a0;
            t = xs.y + xr[1]; t = (t >= 0.f) ? t : 0.2f * t; lg += t * a1;
            t = xs.z + xr[2]; t = (t >= 0.f) ? t : 0.2f * t; lg += t * a2;
            t = xs.w + xr[3]; t = (t >= 0.f) ? t : 0.2f * t; lg += t * a3;
            t = xs4  + xr[4]; t = (t >= 0.f) ? t : 0.2f * t; lg += t * a4;
            const float w = __expf(lg);

            const size_t d5 = (size_t)node * 5;
            const float inv = 1.0f / (acc[l * 6 + 5] + w);
            float v;
            v = (acc[l * 6 + 0] + w * xs.x) * inv + b0; xo[d5 + 0] = (v >= 0.f) ? v : 0.1f * v;
            v = (acc[l * 6 + 1] + w * xs.y) * inv + b1; xo[d5 + 1] = (v >= 0.f) ? v : 0.1f * v;
            v = (acc[l * 6 + 2] + w * xs.z) * inv + b2; xo[d5 + 2] = (v >= 0.f) ? v : 0.1f * v;
            v = (acc[l * 6 + 3] + w * xs.w) * inv + b3; xo[d5 + 3] = (v >= 0.f) ? v : 0.1f * v;
            v = (acc[l * 6 + 4] + w * xs4 ) * inv + b4; xo[d5 + 4] = (v >= 0.f) ? v : 0.1f * v;
        }
        return;
    }

    // ======================= MLP =======================
    if (mode == M_MLP) {
        float* sW = (float*)smem_raw;            // 257 floats
        if (tid < 150) sW[tid] = Wp1[tid];
        if (tid < 10)  sW[150 + tid] = bp1[tid];
        if (tid < 50)  sW[160 + tid] = Wp2[tid];
        if (tid < 5)   sW[210 + tid] = bp2[tid];
        if (tid < 25)  sW[215 + tid] = Wc1[tid];
        if (tid < 5)   sW[240 + tid] = bc1[tid];
        if (tid < 10)  sW[245 + tid] = Wc2[tid];
        if (tid < 2)   sW[255 + tid] = bc2[tid];
        __syncthreads();

        const int node = bx * 256 + tid;
        if (node >= n) return;
        const size_t n5 = (size_t)node * KOUT;

        float h[15];
#pragma unroll
        for (int k = 0; k < 5; ++k) {
            h[k]      = xout[n5 + k];
            h[5 + k]  = xout[(size_t)5 * n + n5 + k];
            h[10 + k] = xout[(size_t)10 * n + n5 + k];
        }

        float t1[10];
#pragma unroll
        for (int o = 0; o < 10; ++o) {
            float a = sW[150 + o];
#pragma unroll
            for (int i = 0; i < 15; ++i) a += h[i] * sW[i * 10 + o];
            t1[o] = (a >= 0.f) ? a : 0.1f * a;
        }
        float t2[5];
#pragma unroll
        for (int o = 0; o < 5; ++o) {
            float a = sW[210 + o];
#pragma unroll
            for (int i = 0; i < 10; ++i) a += t1[i] * sW[160 + i * 5 + o];
            t2[o] = a;
        }
        float t3[5];
#pragma unroll
        for (int o = 0; o < 5; ++o) {
            float a = sW[240 + o];
#pragma unroll
            for (int i = 0; i < 5; ++i) a += t2[i] * sW[215 + i * 5 + o];
            t3[o] = (a >= 0.f) ? a : 0.1f * a;
        }
        float o0 = sW[255], o1 = sW[256];
#pragma unroll
        for (int i = 0; i < 5; ++i) {
            o0 += t3[i] * sW[245 + i * 2 + 0];
            o1 += t3[i] * sW[245 + i * 2 + 1];
        }
        outp[(size_t)node * 2 + 0] = o0;
        outp[(size_t)node * 2 + 1] = o1;
        return;
    }
}

// ---------------------------------------------------------------------------
extern "C" void kernel_launch(void* const* d_in, const int* in_sizes, int n_in,
                              void* d_out, int out_size, void* d_ws, size_t ws_size,
                              hipStream_t stream)
{
    const float* x = (const float*)d_in[0];
    const int n = in_sizes[0] / KIN;          // 1,000,000
    const int E = in_sizes[1] / 2;            // 8,000,000
    const int NB = (n + NPB - 1) >> BSH;      // 1954 (needs n <= 2^20)

    const int* ei[3] = { (const int*)d_in[1], (const int*)d_in[2], (const int*)d_in[3] };
    const float *Wl[3], *Wr[3], *att[3], *bias[3];
    for (int r = 0; r < 3; ++r) {
        const int base = 4 + r * 4;
        Wl[r]   = (const float*)d_in[base + 0];
        Wr[r]   = (const float*)d_in[base + 1];
        att[r]  = (const float*)d_in[base + 2];
        bias[r] = (const float*)d_in[base + 3];
    }
    const float* Wp1 = (const float*)d_in[16];
    const float* bp1 = (const float*)d_in[17];
    const float* Wp2 = (const float*)d_in[18];
    const float* bp2 = (const float*)d_in[19];
    const float* Wc1 = (const float*)d_in[20];
    const float* bc1 = (const float*)d_in[21];
    const float* Wc2 = (const float*)d_in[22];
    const float* bc2 = (const float*)d_in[23];

    // Layout (hist_r overlays xout[r], 16MB <= 20MB slice):
    //  fused (~313MB): xout[15n] | xl8[3][8n] | xr5[3][5n] | rs3[3E] |
    //                  totals3[3*NBH] | base3[3*BROW]
    //  fallback(~145MB): xout[15n] | xl8[8n] | xr5[5n] | rs[E] | totals3 | base3
    const size_t intsA = (size_t)3 * E + 3 * NBH + 3 * BROW;
    const size_t need_A = ((size_t)54 * n + intsA) * 4;
    const bool fused = ws_size >= need_A;
    const int slotmul = fused ? 1 : 0;

    float* ws   = (float*)d_ws;
    float* xout = ws;
    float* xl8  = ws + (size_t)15 * n;
    float* xr5  = xl8 + (fused ? (size_t)24 * n : (size_t)8 * n);
    int*   rs3  = (int*)(xr5 + (fused ? (size_t)15 * n : (size_t)5 * n));
    int*   totals3 = rs3 + (fused ? (size_t)3 * E : (size_t)E);
    int*   base3   = totals3 + 3 * NBH;

    const int NNB  = (n + 1023) / 1024;       // node groups
    const int NMLP = (n + 255) / 256;

    const size_t L_NODE = 28672, L_TAB = 8192, L_SCAN = 1024,
                 L_GATH = 46080, L_MLP = 1056;

#define ARGS x, ei[0], ei[1], ei[2],                                          \
    Wl[0], Wr[0], Wl[1], Wr[1], Wl[2], Wr[2],                                 \
    att[0], att[1], att[2], bias[0], bias[1], bias[2],                        \
    Wp1, bp1, Wp2, bp2, Wc1, bc1, Wc2, bc2,                                   \
    xl8, xr5, rs3, slotmul, totals3, base3, xout, (float*)d_out, n, E, NB
#define L(m0,r0,n0,m1,r1,n1,m2,r2,n2,lds)                                     \
    k_combo<<<(n0)+(n1)+(n2), 256, (lds), stream>>>(                          \
        m0,r0,n0, m1,r1,n1, m2,r2,n2, ARGS)

    if (fused) {
        // software-pipelined schedule: rel pipelines staggered so gathers
        // (fetch-bound) overlap scatters/hists (LDS-atomic-bound).
        L(M_NODE,-1,NNB,   M_HIST,0,NBLK2,  M_NONE,0,0,  L_NODE);
        L(M_HIST,1,NBLK2,  M_SUMO,0,8,      M_NONE,0,0,  L_TAB);
        L(M_HIST,2,NBLK2,  M_SCAN,0,1,      M_NONE,0,0,  L_TAB);
        L(M_SCAT,0,NBLK2,  M_SUMO,1,8,      M_NONE,0,0,  L_TAB);
        L(M_SUMO,2,8,      M_SCAN,1,1,      M_NONE,0,0,  L_SCAN);
        L(M_GATH,0,NB,     M_SCAT,1,NBLK2,  M_SCAN,2,1,  L_GATH);
        L(M_GATH,1,NB,     M_SCAT,2,NBLK2,  M_NONE,0,0,  L_GATH);
        L(M_GATH,2,NB,     M_NONE,0,0,      M_NONE,0,0,  L_GATH);
        L(M_MLP,0,NMLP,    M_NONE,0,0,      M_NONE,0,0,  L_MLP);
    } else {
        // serial fallback (small ws): per-relation pipelines, shared slots.
        for (int r = 0; r < 3; ++r) {
            L(M_NODE,r,NNB,   M_HIST,r,NBLK2, M_NONE,0,0, L_NODE);
            L(M_SUMO,r,8,     M_NONE,0,0,     M_NONE,0,0, L_TAB);
            L(M_SCAN,r,1,     M_NONE,0,0,     M_NONE,0,0, L_SCAN);
            L(M_SCAT,r,NBLK2, M_NONE,0,0,     M_NONE,0,0, L_TAB);
            L(M_GATH,r,NB,    M_NONE,0,0,     M_NONE,0,0, L_GATH);
        }
        L(M_MLP,0,NMLP, M_NONE,0,0, M_NONE,0,0, L_MLP);
    }
#undef L
#undef ARGS
}

// Round 13
// 1045.396 us; speedup vs baseline: 1.2186x; 1.2186x over previous
//
#include <hip/hip_runtime.h>

static constexpr int KIN  = 25;
static constexpr int KOUT = 5;
static constexpr int NBLK = 512;      // blocks for hist/scatter
static constexpr int BTH  = 1024;     // threads for hist/scatter
static constexpr int BSH  = 9;        // log2 nodes per bucket
static constexpr int NPB  = 1 << BSH; // 512 nodes per bucket
static constexpr int NBH  = 2048;     // hist row stride / max buckets
static constexpr int BROW = NBH + 1;  // base row stride (incl. sentinel)
static constexpr int CAP  = 5120;     // max edges per bucket for LDS sort (16 sigma)
static constexpr int GT   = 512;      // gather threads per block

// ---------------------------------------------------------------------------
// k_node1: single-relation transforms (fallback layout).
// ---------------------------------------------------------------------------
__global__ __launch_bounds__(256) void k_node1(
    const float* __restrict__ x,
    const float* __restrict__ Wl, const float* __restrict__ Wr,
    float* __restrict__ xl8, float* __restrict__ xr5, int n)
{
    __shared__ float sWl[KIN * KOUT];
    __shared__ float sWr[KIN * KOUT];
    __shared__ float sx[256 * KIN];

    const int tid = threadIdx.x;
    if (tid < KIN * KOUT) { sWl[tid] = Wl[tid]; sWr[tid] = Wr[tid]; }

    const int base = blockIdx.x * 256;
    const int cnt  = min(256, n - base);
    const size_t xbase = (size_t)base * KIN;
    for (int i = tid; i < cnt * KIN; i += 256) sx[i] = x[xbase + i];
    __syncthreads();

    if (tid >= cnt) return;
    const int node = base + tid;

    float xls[KOUT] = {0.f, 0.f, 0.f, 0.f, 0.f};
    float xrs[KOUT] = {0.f, 0.f, 0.f, 0.f, 0.f};
    const float* xp = &sx[tid * KIN];
#pragma unroll
    for (int i = 0; i < KIN; ++i) {
        const float xv = xp[i];
#pragma unroll
        for (int o = 0; o < KOUT; ++o) {
            xls[o] += xv * sWl[i * KOUT + o];
            xrs[o] += xv * sWr[i * KOUT + o];
        }
    }

    const size_t n8 = (size_t)node * 8;
    float4 v4;
    v4.x = xls[0]; v4.y = xls[1]; v4.z = xls[2]; v4.w = xls[3];
    *(float4*)(xl8 + n8) = v4;
    xl8[n8 + 4] = xls[4];
    const size_t n5 = (size_t)node * 5;
#pragma unroll
    for (int o = 0; o < KOUT; ++o) xr5[n5 + o] = xrs[o];
}

// ---------------------------------------------------------------------------
// k_histnode: fused dispatch. Blocks x<NBLK: dst-bucket histogram (rel = y,
// int4 edge reads). Blocks x>=NBLK (y==0 only): node transforms for all 3
// relations (independent work overlapped with the histogram).
// ---------------------------------------------------------------------------
__global__ __launch_bounds__(BTH) void k_histnode(
    const int* __restrict__ d0p, const int* __restrict__ d1p,
    const int* __restrict__ d2p, int E, int NB, int* __restrict__ hist3,
    const float* __restrict__ x,
    const float* __restrict__ Wl0, const float* __restrict__ Wr0,
    const float* __restrict__ Wl1, const float* __restrict__ Wr1,
    const float* __restrict__ Wl2, const float* __restrict__ Wr2,
    float* __restrict__ xl8, float* __restrict__ xr5, int n, int NNB)
{
    __shared__ float smem[7424];          // 29 KB (union: hist | weights+sx)
    const int y = blockIdx.y, bx = blockIdx.x, tid = threadIdx.x;

    if (bx < NBLK) {
        // ---- histogram for relation y ----
        int* h = (int*)smem;
        const int* dst = (y == 0) ? d0p : (y == 1 ? d1p : d2p);
        int* hist_blk = hist3 + (size_t)y * NBLK * NBH;
        for (int i = tid; i < NB; i += BTH) h[i] = 0;
        __syncthreads();
        const int chunk = (((E + NBLK - 1) / NBLK) + 3) & ~3;
        const int eb = bx * chunk, ee = min(E, eb + chunk);
        const int vend = eb + ((ee - eb) & ~3);
        for (int i = eb + tid * 4; i < vend; i += BTH * 4) {
            const int4 d4 = *(const int4*)(dst + i);
            atomicAdd(&h[d4.x >> BSH], 1);
            atomicAdd(&h[d4.y >> BSH], 1);
            atomicAdd(&h[d4.z >> BSH], 1);
            atomicAdd(&h[d4.w >> BSH], 1);
        }
        for (int i = vend + tid; i < ee; i += BTH)
            atomicAdd(&h[dst[i] >> BSH], 1);
        __syncthreads();
        for (int i = tid; i < NB; i += BTH) hist_blk[bx * NBH + i] = h[i];
        return;
    }

    // ---- node transforms (y == 0 row only) ----
    if (y != 0) return;
    const int g = bx - NBLK;
    if (g >= NNB) return;

    float* sW = smem;                     // 6 x 125
    float* sx = smem + 768;               // 256 x 25
    if (tid < KIN * KOUT) {
        sW[tid]       = Wl0[tid]; sW[125 + tid] = Wr0[tid];
        sW[250 + tid] = Wl1[tid]; sW[375 + tid] = Wr1[tid];
        sW[500 + tid] = Wl2[tid]; sW[625 + tid] = Wr2[tid];
    }

    for (int sub = 0; sub < 4; ++sub) {
        const int base = g * 1024 + sub * 256;
        if (base >= n) break;
        const int cnt = min(256, n - base);
        __syncthreads();
        const size_t xb = (size_t)base * KIN;
        for (int i = tid; i < cnt * KIN; i += BTH) sx[i] = x[xb + i];
        __syncthreads();
        if (tid < cnt) {
            const int node = base + tid;
            float xls[3][KOUT] = {};
            float xrs[3][KOUT] = {};
            const float* xp = &sx[tid * KIN];
#pragma unroll
            for (int i = 0; i < KIN; ++i) {
                const float xv = xp[i];
#pragma unroll
                for (int r = 0; r < 3; ++r)
#pragma unroll
                    for (int o = 0; o < KOUT; ++o) {
                        xls[r][o] += xv * sW[r * 250 + i * KOUT + o];
                        xrs[r][o] += xv * sW[r * 250 + 125 + i * KOUT + o];
                    }
            }
#pragma unroll
            for (int r = 0; r < 3; ++r) {
                const size_t n8 = (size_t)r * n * 8 + (size_t)node * 8;
                float4 v4;
                v4.x = xls[r][0]; v4.y = xls[r][1];
                v4.z = xls[r][2]; v4.w = xls[r][3];
                *(float4*)(xl8 + n8) = v4;
                xl8[n8 + 4] = xls[r][4];
                const size_t n5 = (size_t)r * n * 5 + (size_t)node * 5;
#pragma unroll
                for (int o = 0; o < KOUT; ++o) xr5[n5 + o] = xrs[r][o];
            }
        }
    }
}

// ---------------------------------------------------------------------------
// k_sumoffs3: per bucket, hist rows -> exclusive per-block offsets + totals.
// ---------------------------------------------------------------------------
__global__ __launch_bounds__(256) void k_sumoffs3(
    int* __restrict__ hist3, int NB, int* __restrict__ totals3)
{
    const int rel = blockIdx.y;
    int* hist_blk = hist3 + (size_t)rel * NBLK * NBH;
    int* totals   = totals3 + rel * NBH;
    const int i = blockIdx.x * 256 + threadIdx.x;
    if (i >= NB) return;
    int s = 0;
    for (int b = 0; b < NBLK; ++b) {
        const int t = hist_blk[b * NBH + i];
        hist_blk[b * NBH + i] = s;
        s += t;
    }
    totals[i] = s;
}

// ---------------------------------------------------------------------------
// k_scan3: exclusive scan of totals -> base per relation. blockIdx.x = rel.
// ---------------------------------------------------------------------------
__global__ __launch_bounds__(1024) void k_scan3(
    const int* __restrict__ totals3, int E, int NB, int* __restrict__ base3)
{
    __shared__ int s[1024];
    const int rel = blockIdx.x;
    const int* totals = totals3 + rel * NBH;
    int* base = base3 + rel * BROW;

    const int t = threadIdx.x;
    const int i0 = 2 * t, i1 = 2 * t + 1;
    const int t0 = (i0 < NB) ? totals[i0] : 0;
    const int t1 = (i1 < NB) ? totals[i1] : 0;
    const int pair = t0 + t1;
    s[t] = pair;
    __syncthreads();
    for (int off = 1; off < 1024; off <<= 1) {
        int v = (t >= off) ? s[t - off] : 0;
        __syncthreads();
        s[t] += v;
        __syncthreads();
    }
    const int excl = s[t] - pair;
    base[i0] = excl;
    base[i1] = excl + t0;
    if (t == 1023) base[NBH] = E;
}

// ---------------------------------------------------------------------------
// k_scatter3: single pass, no global atomics, int4 edge reads.
// ---------------------------------------------------------------------------
__global__ __launch_bounds__(BTH) void k_scatter3(
    const int* __restrict__ s0p, const int* __restrict__ s1p,
    const int* __restrict__ s2p,
    const int* __restrict__ d0p, const int* __restrict__ d1p,
    const int* __restrict__ d2p,
    int E, int NB,
    const int* __restrict__ hist3, const int* __restrict__ base3,
    int* __restrict__ rs3)
{
    __shared__ int cur[NBH];
    const int rel = blockIdx.y, b = blockIdx.x, tid = threadIdx.x;
    const int* src = (rel == 0) ? s0p : (rel == 1 ? s1p : s2p);
    const int* dst = (rel == 0) ? d0p : (rel == 1 ? d1p : d2p);
    const int* hist_blk = hist3 + (size_t)rel * NBLK * NBH;
    const int* base = base3 + rel * BROW;
    int* rs = rs3 + (size_t)rel * E;

    for (int i = tid; i < NB; i += BTH)
        cur[i] = base[i] + hist_blk[b * NBH + i];
    __syncthreads();
    const int chunk = (((E + NBLK - 1) / NBLK) + 3) & ~3;
    const int eb = b * chunk, ee = min(E, eb + chunk);
    const int vend = eb + ((ee - eb) & ~3);
    for (int i = eb + tid * 4; i < vend; i += BTH * 4) {
        const int4 s4 = *(const int4*)(src + i);
        const int4 d4 = *(const int4*)(dst + i);
        int p;
        p = atomicAdd(&cur[d4.x >> BSH], 1); rs[p] = (s4.x << BSH) | (d4.x & (NPB - 1));
        p = atomicAdd(&cur[d4.y >> BSH], 1); rs[p] = (s4.y << BSH) | (d4.y & (NPB - 1));
        p = atomicAdd(&cur[d4.z >> BSH], 1); rs[p] = (s4.z << BSH) | (d4.z & (NPB - 1));
        p = atomicAdd(&cur[d4.w >> BSH], 1); rs[p] = (s4.w << BSH) | (d4.w & (NPB - 1));
    }
    for (int i = vend + tid; i < ee; i += BTH) {
        const int d = dst[i];
        const int pos = atomicAdd(&cur[d >> BSH], 1);
        rs[pos] = (src[i] << BSH) | (d & (NPB - 1));
    }
}

// ---------------------------------------------------------------------------
// k_gather4: one block per (relation, bucket), REL-MAJOR order, GT=512
// threads (24 waves/CU at 3 blocks -> 2x memory-level parallelism vs 256).
// In-LDS counting sort by dst-local, then chunked register accumulation.
// ---------------------------------------------------------------------------
template <int NREL>
__global__ __launch_bounds__(GT) void k_gather4(
    const int* __restrict__ rs3, const int* __restrict__ base3,
    const float* __restrict__ xl8a, const float* __restrict__ xr5a,
    const float* __restrict__ at0, const float* __restrict__ at1,
    const float* __restrict__ at2,
    const float* __restrict__ bi0, const float* __restrict__ bi1,
    const float* __restrict__ bi2,
    float* __restrict__ xouta, int n, int E, int NB)
{
    __shared__ float acc[NPB][6];       // 12 KB
    __shared__ float xrw[NPB * 5];      // 10 KB
    __shared__ int   cur[NPB];          // 2 KB
    __shared__ int   sorted[CAP];       // 20 KB
    __shared__ int   sc[GT];            // 2 KB

    const int bx  = blockIdx.x;
    const int rel = (NREL == 1) ? 0 : bx / NB;     // rel-major
    const int bkt = (NREL == 1) ? bx : bx % NB;

    const int*   rs   = rs3 + (size_t)rel * E;
    const int*   base = base3 + rel * BROW;
    const float* xl8  = xl8a + (size_t)rel * 8 * n;
    const float* xr5  = xr5a + (size_t)rel * 5 * n;
    const float* att  = (rel == 0) ? at0 : (rel == 1 ? at1 : at2);
    const float* bias = (rel == 0) ? bi0 : (rel == 1 ? bi1 : bi2);
    float*       xout = xouta + (size_t)rel * 5 * n;

    const int tid = threadIdx.x;
    const int node0 = bkt << BSH;
    const int nn = min(NPB, n - node0);

    for (int i = tid; i < NPB * 6; i += GT) ((float*)acc)[i] = 0.f;
    for (int i = tid; i < nn * 5; i += GT) xrw[i] = xr5[(size_t)node0 * 5 + i];
    for (int i = tid; i < NPB; i += GT) cur[i] = 0;
    __syncthreads();

    const float a0 = att[0], a1 = att[1], a2 = att[2], a3 = att[3], a4 = att[4];
    const int eb = base[bkt], ee = base[bkt + 1];
    const int seg = ee - eb;

    if (seg > 0 && seg <= CAP) {
        for (int i = eb + tid; i < ee; i += GT)
            atomicAdd(&cur[rs[i] & (NPB - 1)], 1);
        __syncthreads();
        // 512 bins scanned by 512 threads, 1 bin each
        const int h0 = cur[tid];
        sc[tid] = h0;
        __syncthreads();
        for (int off = 1; off < GT; off <<= 1) {
            const int v = (tid >= off) ? sc[tid - off] : 0;
            __syncthreads();
            sc[tid] += v;
            __syncthreads();
        }
        cur[tid] = sc[tid] - h0;            // exclusive
        __syncthreads();
        for (int i = eb + tid; i < ee; i += GT) {
            const int v = rs[i];
            const int p = atomicAdd(&cur[v & (NPB - 1)], 1);
            sorted[p] = v;
        }
        __syncthreads();
        const int C  = (seg + GT - 1) / GT;
        const int s0 = tid * C;
        const int s1 = min(seg, s0 + C);
        int curdl = -1;
        float A0 = 0.f, A1 = 0.f, A2 = 0.f, A3 = 0.f, A4 = 0.f, A5 = 0.f;
        float xr0 = 0.f, xr1 = 0.f, xr2 = 0.f, xr3 = 0.f, xr4 = 0.f;
        for (int i = s0; i < s1; ++i) {
            const int v  = sorted[i];
            const int dl = v & (NPB - 1);
            const int s  = v >> BSH;
            const size_t s8 = (size_t)s * 8;
            const float4 xs = *(const float4*)(xl8 + s8);
            const float  xs4 = xl8[s8 + 4];
            if (dl != curdl) {
                if (curdl >= 0) {
                    atomicAdd(&acc[curdl][0], A0);
                    atomicAdd(&acc[curdl][1], A1);
                    atomicAdd(&acc[curdl][2], A2);
                    atomicAdd(&acc[curdl][3], A3);
                    atomicAdd(&acc[curdl][4], A4);
                    atomicAdd(&acc[curdl][5], A5);
                }
                curdl = dl;
                A0 = A1 = A2 = A3 = A4 = A5 = 0.f;
                const float* xr = &xrw[dl * 5];
                xr0 = xr[0]; xr1 = xr[1]; xr2 = xr[2]; xr3 = xr[3]; xr4 = xr[4];
            }
            float t, lg = 0.f;
            t = xs.x + xr0; t = (t >= 0.f) ? t : 0.2f * t; lg += t * a0;
            t = xs.y + xr1; t = (t >= 0.f) ? t : 0.2f * t; lg += t * a1;
            t = xs.z + xr2; t = (t >= 0.f) ? t : 0.2f * t; lg += t * a2;
            t = xs.w + xr3; t = (t >= 0.f) ? t : 0.2f * t; lg += t * a3;
            t = xs4  + xr4; t = (t >= 0.f) ? t : 0.2f * t; lg += t * a4;
            const float w = __expf(lg);
            A0 += w * xs.x; A1 += w * xs.y; A2 += w * xs.z;
            A3 += w * xs.w; A4 += w * xs4;  A5 += w;
        }
        if (curdl >= 0) {
            atomicAdd(&acc[curdl][0], A0);
            atomicAdd(&acc[curdl][1], A1);
            atomicAdd(&acc[curdl][2], A2);
            atomicAdd(&acc[curdl][3], A3);
            atomicAdd(&acc[curdl][4], A4);
            atomicAdd(&acc[curdl][5], A5);
        }
        __syncthreads();
    } else if (seg > CAP) {
        for (int i = eb + tid; i < ee; i += GT) {
            const int v  = rs[i];
            const int s  = v >> BSH;
            const int dl = v & (NPB - 1);
            const size_t s8 = (size_t)s * 8;
            const float4 xs = *(const float4*)(xl8 + s8);
            const float  xs4 = xl8[s8 + 4];
            const float* xr = &xrw[dl * 5];
            float t, lg = 0.f;
            t = xs.x + xr[0]; t = (t >= 0.f) ? t : 0.2f * t; lg += t * a0;
            t = xs.y + xr[1]; t = (t >= 0.f) ? t : 0.2f * t; lg += t * a1;
            t = xs.z + xr[2]; t = (t >= 0.f) ? t : 0.2f * t; lg += t * a2;
            t = xs.w + xr[3]; t = (t >= 0.f) ? t : 0.2f * t; lg += t * a3;
            t = xs4  + xr[4]; t = (t >= 0.f) ? t : 0.2f * t; lg += t * a4;
            const float w = __expf(lg);
            atomicAdd(&acc[dl][0], w * xs.x);
            atomicAdd(&acc[dl][1], w * xs.y);
            atomicAdd(&acc[dl][2], w * xs.z);
            atomicAdd(&acc[dl][3], w * xs.w);
            atomicAdd(&acc[dl][4], w * xs4);
            atomicAdd(&acc[dl][5], w);
        }
        __syncthreads();
    } else {
        __syncthreads();
    }

    const float b0 = bias[0], b1 = bias[1], b2 = bias[2], b3 = bias[3], b4 = bias[4];
    for (int l = tid; l < nn; l += GT) {
        const int node = node0 + l;
        const size_t s8 = (size_t)node * 8;
        const float4 xs = *(const float4*)(xl8 + s8);
        const float  xs4 = xl8[s8 + 4];
        const float* xr = &xrw[l * 5];

        float t, lg = 0.f;
        t = xs.x + xr[0]; t = (t >= 0.f) ? t : 0.2f * t; lg += t * a0;
        t = xs.y + xr[1]; t = (t >= 0.f) ? t : 0.2f * t; lg += t * a1;
        t = xs.z + xr[2]; t = (t >= 0.f) ? t : 0.2f * t; lg += t * a2;
        t = xs.w + xr[3]; t = (t >= 0.f) ? t : 0.2f * t; lg += t * a3;
        t = xs4  + xr[4]; t = (t >= 0.f) ? t : 0.2f * t; lg += t * a4;
        const float w = __expf(lg);

        const size_t d5 = (size_t)node * 5;
        const float inv = 1.0f / (acc[l][5] + w);
        float v;
        v = (acc[l][0] + w * xs.x) * inv + b0; xout[d5 + 0] = (v >= 0.f) ? v : 0.1f * v;
        v = (acc[l][1] + w * xs.y) * inv + b1; xout[d5 + 1] = (v >= 0.f) ? v : 0.1f * v;
        v = (acc[l][2] + w * xs.z) * inv + b2; xout[d5 + 2] = (v >= 0.f) ? v : 0.1f * v;
        v = (acc[l][3] + w * xs.w) * inv + b3; xout[d5 + 3] = (v >= 0.f) ? v : 0.1f * v;
        v = (acc[l][4] + w * xs4 ) * inv + b4; xout[d5 + 4] = (v >= 0.f) ? v : 0.1f * v;
    }
}

// ---------------------------------------------------------------------------
// k_mlp: fused projection + classifier.
// ---------------------------------------------------------------------------
__global__ __launch_bounds__(256) void k_mlp(
    const float* __restrict__ xp, const float* __restrict__ xs,
    const float* __restrict__ xv,
    const float* __restrict__ Wp1, const float* __restrict__ bp1,
    const float* __restrict__ Wp2, const float* __restrict__ bp2,
    const float* __restrict__ Wc1, const float* __restrict__ bc1,
    const float* __restrict__ Wc2, const float* __restrict__ bc2,
    float* __restrict__ out, int n)
{
    __shared__ float sW[257];
    const int tid = threadIdx.x;
    if (tid < 150) sW[tid] = Wp1[tid];
    if (tid < 10)  sW[150 + tid] = bp1[tid];
    if (tid < 50)  sW[160 + tid] = Wp2[tid];
    if (tid < 5)   sW[210 + tid] = bp2[tid];
    if (tid < 25)  sW[215 + tid] = Wc1[tid];
    if (tid < 5)   sW[240 + tid] = bc1[tid];
    if (tid < 10)  sW[245 + tid] = Wc2[tid];
    if (tid < 2)   sW[255 + tid] = bc2[tid];
    __syncthreads();

    const int node = blockIdx.x * 256 + tid;
    if (node >= n) return;
    const size_t n5 = (size_t)node * KOUT;

    float h[15];
#pragma unroll
    for (int k = 0; k < 5; ++k) {
        h[k]      = xp[n5 + k];
        h[5 + k]  = xs[n5 + k];
        h[10 + k] = xv[n5 + k];
    }

    float t1[10];
#pragma unroll
    for (int o = 0; o < 10; ++o) {
        float a = sW[150 + o];
#pragma unroll
        for (int i = 0; i < 15; ++i) a += h[i] * sW[i * 10 + o];
        t1[o] = (a >= 0.f) ? a : 0.1f * a;
    }

    float t2[5];
#pragma unroll
    for (int o = 0; o < 5; ++o) {
        float a = sW[210 + o];
#pragma unroll
        for (int i = 0; i < 10; ++i) a += t1[i] * sW[160 + i * 5 + o];
        t2[o] = a;
    }

    float t3[5];
#pragma unroll
    for (int o = 0; o < 5; ++o) {
        float a = sW[240 + o];
#pragma unroll
        for (int i = 0; i < 5; ++i) a += t2[i] * sW[215 + i * 5 + o];
        t3[o] = (a >= 0.f) ? a : 0.1f * a;
    }

    float o0 = sW[255], o1 = sW[256];
#pragma unroll
    for (int i = 0; i < 5; ++i) {
        o0 += t3[i] * sW[245 + i * 2 + 0];
        o1 += t3[i] * sW[245 + i * 2 + 1];
    }
    out[(size_t)node * 2 + 0] = o0;
    out[(size_t)node * 2 + 1] = o1;
}

// ---------------------------------------------------------------------------
extern "C" void kernel_launch(void* const* d_in, const int* in_sizes, int n_in,
                              void* d_out, int out_size, void* d_ws, size_t ws_size,
                              hipStream_t stream)
{
    const float* x = (const float*)d_in[0];
    const int n = in_sizes[0] / KIN;          // 1,000,000
    const int E = in_sizes[1] / 2;            // 8,000,000
    const int NB = (n + NPB - 1) >> BSH;      // 1954 buckets (needs n <= 2^20)

    const int* ei[3] = { (const int*)d_in[1], (const int*)d_in[2], (const int*)d_in[3] };
    const float *Wl[3], *Wr[3], *att[3], *bias[3];
    for (int r = 0; r < 3; ++r) {
        const int base = 4 + r * 4;
        Wl[r]   = (const float*)d_in[base + 0];
        Wr[r]   = (const float*)d_in[base + 1];
        att[r]  = (const float*)d_in[base + 2];
        bias[r] = (const float*)d_in[base + 3];
    }
    const float* Wp1 = (const float*)d_in[16];
    const float* bp1 = (const float*)d_in[17];
    const float* Wp2 = (const float*)d_in[18];
    const float* bp2 = (const float*)d_in[19];
    const float* Wc1 = (const float*)d_in[20];
    const float* bc1 = (const float*)d_in[21];
    const float* Wc2 = (const float*)d_in[22];
    const float* bc2 = (const float*)d_in[23];

    // Fused layout A (~313MB): xout[15n] | xl8[3][8n] | xr5[3][5n] |
    //   rs3[3E] | totals3[3*NBH] | base3[3*BROW]
    // Fallback layout B (~144MB): xout[15n] | xl8[8n] | xr5[5n] |
    //   rs[E] | totals[NBH] | base[BROW]
    // hist3 overlays xout[10n..15n) (dead until last gather writes it).
    const size_t intsA = (size_t)3 * E + 3 * NBH + 3 * BROW;
    const size_t need_A = ((size_t)54 * n + intsA) * 4;
    const bool fused = ws_size >= need_A;

    float* ws   = (float*)d_ws;
    float* xout = ws;
    float* xl8  = ws + (size_t)15 * n;
    float* xr5  = xl8 + (fused ? (size_t)24 * n : (size_t)8 * n);
    int*   rs3  = (int*)(xr5 + (fused ? (size_t)15 * n : (size_t)5 * n));
    int*   totals3 = rs3 + (fused ? (size_t)3 * E : (size_t)E);
    int*   base3   = totals3 + (fused ? 3 * NBH : NBH);
    int*   hist3   = (int*)(xout + (size_t)10 * n);   // overlay on xv slice

    const int nb_node = (n + 255) / 256;
    const int nb_cols = (NB + 255) / 256;
    const int NNB     = (n + 1023) / 1024;            // node groups (1024/blk)

    if (fused) {
        k_histnode<<<dim3(NBLK + NNB, 3), BTH, 0, stream>>>(
            ei[0] + E, ei[1] + E, ei[2] + E, E, NB, hist3,
            x, Wl[0], Wr[0], Wl[1], Wr[1], Wl[2], Wr[2], xl8, xr5, n, NNB);
        k_sumoffs3<<<dim3(nb_cols, 3), 256,  0, stream>>>(hist3, NB, totals3);
        k_scan3   <<<3,                1024, 0, stream>>>(totals3, E, NB, base3);
        k_scatter3<<<dim3(NBLK, 3),    BTH,  0, stream>>>(
            ei[0], ei[1], ei[2], ei[0] + E, ei[1] + E, ei[2] + E,
            E, NB, hist3, base3, rs3);
        k_gather4<3><<<3 * NB, GT, 0, stream>>>(
            rs3, base3, xl8, xr5,
            att[0], att[1], att[2], bias[0], bias[1], bias[2],
            xout, n, E, NB);
    } else {
        for (int r = 0; r < 3; ++r) {
            float* xo = xout + (size_t)r * 5 * n;
            k_node1<<<nb_node, 256, 0, stream>>>(x, Wl[r], Wr[r], xl8, xr5, n);
            k_histnode<<<dim3(NBLK, 1), BTH, 0, stream>>>(
                ei[r] + E, ei[r] + E, ei[r] + E, E, NB, hist3,
                x, Wl[r], Wr[r], Wl[r], Wr[r], Wl[r], Wr[r], xl8, xr5, n, 0);
            k_sumoffs3<<<dim3(nb_cols, 1), 256,  0, stream>>>(hist3, NB, totals3);
            k_scan3   <<<1,                1024, 0, stream>>>(totals3, E, NB, base3);
            k_scatter3<<<dim3(NBLK, 1),    BTH,  0, stream>>>(
                ei[r], ei[r], ei[r], ei[r] + E, ei[r] + E, ei[r] + E,
                E, NB, hist3, base3, rs3);
            k_gather4<1><<<NB, GT, 0, stream>>>(
                rs3, base3, xl8, xr5,
                att[r], att[r], att[r], bias[r], bias[r], bias[r],
                xo, n, E, NB);
        }
    }

    k_mlp<<<nb_node, 256, 0, stream>>>(xout, xout + (size_t)5 * n, xout + (size_t)10 * n,
                                       Wp1, bp1, Wp2, bp2, Wc1, bc1, Wc2, bc2,
                                       (float*)d_out, n);
}